// Round 1
// baseline (447.165 us; speedup 1.0000x reference)
//
#include <hip/hip_runtime.h>

// HierarchicalSoftmax: out[b, c*320 + t] = (x_b · topW[:,c] + top_b[c]) + (x_b · botW[t,:] + bot_b[t])
// B=1024, NHID=128, NCLASSES=320, PER_CLASS=320, row = 102400 fp32.
// Write-bound: 419.4 MB out -> floor ~67 us @ 6.3 TB/s.

#define BATCH      1024
#define NHID       128
#define NCLASSES   320
#define PER_CLASS  320
#define ROW_ELEMS  (NCLASSES * PER_CLASS)   // 102400
#define ROW_F4     (ROW_ELEMS / 4)          // 25600
#define PC_F4      (PER_CLASS / 4)          // 80

typedef float f32x4 __attribute__((ext_vector_type(4)));

__global__ __launch_bounds__(256) void hs_fused_kernel(
    const float* __restrict__ inputs,     // [B, NHID]
    const float* __restrict__ top_W,      // [NHID, NCLASSES] row-major (k-major)
    const float* __restrict__ top_b,      // [NCLASSES]
    const float* __restrict__ bottom_W,   // [PER_CLASS, NHID] row-major
    const float* __restrict__ bottom_b,   // [NCLASSES] (indexed by t in [0,320))
    float* __restrict__ out)              // [B, ROW_ELEMS]
{
    __shared__ __align__(16) float s_in[NHID];
    __shared__ __align__(16) float s_row[NCLASSES + PER_CLASS]; // [top(320) | bottom(320)]

    const int b   = blockIdx.x;
    const int tid = threadIdx.x;

    // ---- Phase 0: stage input row in LDS ----
    if (tid < NHID) s_in[tid] = inputs[b * NHID + tid];
    __syncthreads();

    // ---- Phase 1: compute top (320) and bottom (320) logits for this row ----
    for (int j = tid; j < NCLASSES + PER_CLASS; j += 256) {
        float acc;
        if (j < NCLASSES) {
            // top logit c=j: sum_k s_in[k] * top_W[k*NCLASSES + c]  (coalesced-ish across j)
            acc = top_b[j];
            #pragma unroll 8
            for (int k = 0; k < NHID; ++k)
                acc += s_in[k] * top_W[k * NCLASSES + j];
        } else {
            // bottom logit t: sum_k s_in[k] * bottom_W[t*NHID + k]  (contiguous per-thread, vec4)
            const int t = j - NCLASSES;
            acc = bottom_b[t];
            const f32x4* w4 = (const f32x4*)(bottom_W + t * NHID);
            #pragma unroll 8
            for (int k4 = 0; k4 < NHID / 4; ++k4) {
                f32x4 w = w4[k4];
                acc += s_in[4 * k4 + 0] * w.x + s_in[4 * k4 + 1] * w.y
                     + s_in[4 * k4 + 2] * w.z + s_in[4 * k4 + 3] * w.w;
            }
        }
        s_row[j] = acc;
    }
    __syncthreads();

    // ---- Phase 2: stream the 102400-float row: out4[g] = top[g/80] + bot4[g%80] ----
    f32x4* outrow = (f32x4*)(out + (size_t)b * ROW_ELEMS);
    const f32x4* bot4 = (const f32x4*)(s_row + NCLASSES);

    #pragma unroll 4
    for (int g = tid; g < ROW_F4; g += 256) {
        const int c  = g / PC_F4;           // constant divide -> magic mul
        const int t4 = g - c * PC_F4;
        const float tv = s_row[c];          // near-broadcast within a wave
        f32x4 bv = bot4[t4];                // ds_read_b128, stride-16B conflict-free
        f32x4 v;
        v.x = tv + bv.x;
        v.y = tv + bv.y;
        v.z = tv + bv.z;
        v.w = tv + bv.w;
        __builtin_nontemporal_store(v, &outrow[g]);
    }
}

extern "C" void kernel_launch(void* const* d_in, const int* in_sizes, int n_in,
                              void* d_out, int out_size, void* d_ws, size_t ws_size,
                              hipStream_t stream) {
    const float* inputs   = (const float*)d_in[0];
    const float* top_W    = (const float*)d_in[1];
    const float* top_b    = (const float*)d_in[2];
    const float* bottom_W = (const float*)d_in[3];
    const float* bottom_b = (const float*)d_in[4];
    float* out = (float*)d_out;

    hs_fused_kernel<<<BATCH, 256, 0, stream>>>(inputs, top_W, top_b, bottom_W, bottom_b, out);
}